// Round 7
// baseline (201.075 us; speedup 1.0000x reference)
//
#include <hip/hip_runtime.h>
#include <hip/hip_bf16.h>

// B=2, S=2048, D=1024, H=16, DK=64, THETA=10000
// Inputs fp32 (positions int32): x[2,2048,1024], token_positions[2048],
// Wq,Wk,Wv,Wo [1024,1024].  Output fp32 [2,2048,1024].
// proj: y[b,s,o] = sum_d x[b,s,d] * W[o,d]

typedef __attribute__((ext_vector_type(8))) short short8;   // 8 bf16 = 4 VGPRs
typedef __attribute__((ext_vector_type(4))) float floatx4;  // MFMA accumulator

static __device__ __forceinline__ unsigned short f2bf(float f) {
  __hip_bfloat16 h = __float2bfloat16(f);
  return *(unsigned short*)&h;
}

// async global->LDS DMA, 16 B per lane; lds base must be wave-uniform,
// HW writes lane i at ldsbase + i*16.
static __device__ __forceinline__ void gl2lds16(const unsigned short* g,
                                                unsigned short* l) {
  __builtin_amdgcn_global_load_lds(
      (const __attribute__((address_space(1))) void*)g,
      (__attribute__((address_space(3))) void*)l, 16, 0, 0);
}

// ---------------------------------------------------------------------------
// fp32 -> bf16 conversion, all 5 tensors in one launch (blockIdx.y selects)
// ---------------------------------------------------------------------------
__global__ __launch_bounds__(256) void cvt_all(
    const float4* __restrict__ x,  const float4* __restrict__ wq,
    const float4* __restrict__ wk, const float4* __restrict__ wv,
    const float4* __restrict__ wo,
    ushort4* __restrict__ xb,  ushort4* __restrict__ wqb,
    ushort4* __restrict__ wkb, ushort4* __restrict__ wvb,
    ushort4* __restrict__ wob) {
  int t = blockIdx.y;
  const float4* s = (t == 0) ? x : (t == 1) ? wq : (t == 2) ? wk : (t == 3) ? wv : wo;
  ushort4* d = (t == 0) ? xb : (t == 1) ? wqb : (t == 2) ? wkb : (t == 3) ? wvb : wob;
  int n4 = (t == 0) ? 1048576 : 262144;
  int i = blockIdx.x * 256 + threadIdx.x;
  if (i < n4) {
    float4 v = s[i];
    ushort4 o;
    o.x = f2bf(v.x); o.y = f2bf(v.y); o.z = f2bf(v.z); o.w = f2bf(v.w);
    d[i] = o;
  }
}

// ---------------------------------------------------------------------------
// RoPE cos/sin tables, fp32, [s][pair 0..31]
// ---------------------------------------------------------------------------
__global__ void rope_tables(const int* __restrict__ tokpos,
                            float* __restrict__ ctab, float* __restrict__ stab) {
  int idx = blockIdx.x * 256 + threadIdx.x;  // 65536
  int s = idx >> 5;
  int i = idx & 31;
  float inv = expf(-9.210340371976184f * (float)(2 * i) / 64.0f);
  float ang = (float)tokpos[s] * inv;
  ctab[idx] = cosf(ang);
  stab[idx] = sinf(ang);
}

// ---------------------------------------------------------------------------
// 128x128-tile GEMM body, m97 structure: global_load_lds width=16 staging into
// UNPADDED [128][64] LDS tiles with XOR chunk swizzle (LDS[r][c] holds global
// chunk c^(r&7); fragment reads fetch chunk (4ks+quad)^(l15&7) -> 2-way bank
// alias only). C[128][128] = A[128x1024] * W^T, both row-major.
// ---------------------------------------------------------------------------
#define GEMM128_BODY(Aptr, Wptr, m0, n0)                                        \
  __shared__ __align__(16) unsigned short lA[128 * 64];                         \
  __shared__ __align__(16) unsigned short lB[128 * 64];                         \
  int tid = threadIdx.x;                                                        \
  int wave = tid >> 6, lane = tid & 63;                                         \
  int wm = wave >> 1, wn = wave & 1;                                            \
  int l15 = lane & 15, quad = lane >> 4;                                        \
  int srow = wave * 32 + (lane >> 3);  /* staging row (+p*8) */                 \
  int sch = lane & 7;                  /* staging 16B-chunk  */                 \
  int fsw = l15 & 7;                   /* fragment-read swizzle */              \
  floatx4 acc[4][4];                                                            \
  _Pragma("unroll") for (int m = 0; m < 4; ++m)                                 \
      _Pragma("unroll") for (int n = 0; n < 4; ++n)                             \
          acc[m][n] = (floatx4){0.f, 0.f, 0.f, 0.f};                            \
  for (int kt = 0; kt < 16; ++kt) {                                             \
    _Pragma("unroll") for (int p = 0; p < 4; ++p) {                             \
      int r = srow + p * 8;                                                     \
      int g = sch ^ (r & 7);                                                    \
      gl2lds16(Aptr + (size_t)(m0 + r) * 1024 + kt * 64 + g * 8,                \
               lA + (wave * 32 + p * 8) * 64);                                  \
      gl2lds16(Wptr + (size_t)(n0 + r) * 1024 + kt * 64 + g * 8,                \
               lB + (wave * 32 + p * 8) * 64);                                  \
    }                                                                           \
    __syncthreads();                                                            \
    _Pragma("unroll") for (int ks = 0; ks < 2; ++ks) {                          \
      short8 af[4], bf[4];                                                      \
      _Pragma("unroll") for (int m = 0; m < 4; ++m)                             \
          af[m] = *(const short8*)(lA + (wm * 64 + m * 16 + l15) * 64 +         \
                                   (((ks * 4 + quad) ^ fsw) * 8));              \
      _Pragma("unroll") for (int n = 0; n < 4; ++n)                             \
          bf[n] = *(const short8*)(lB + (wn * 64 + n * 16 + l15) * 64 +         \
                                   (((ks * 4 + quad) ^ fsw) * 8));              \
      _Pragma("unroll") for (int m = 0; m < 4; ++m)                             \
          _Pragma("unroll") for (int n = 0; n < 4; ++n)                         \
              acc[m][n] = __builtin_amdgcn_mfma_f32_16x16x32_bf16(              \
                  af[m], bf[n], acc[m][n], 0, 0, 0);                            \
    }                                                                           \
    __syncthreads();                                                            \
  }

// ---------------------------------------------------------------------------
// QKV projection, tiled MFMA GEMM + fused RoPE epilogue.
// Q pre-scaled by 1/sqrt(64). Q,K bf16 [bh][s][64]; V transposed [bh][d][2048].
// ---------------------------------------------------------------------------
__global__ __launch_bounds__(256) void qkv_mfma(
    const unsigned short* __restrict__ X,
    const unsigned short* __restrict__ Wq,
    const unsigned short* __restrict__ Wk,
    const unsigned short* __restrict__ Wv,
    const float* __restrict__ ctab, const float* __restrict__ stab,
    unsigned short* __restrict__ Qo, unsigned short* __restrict__ Ko,
    unsigned short* __restrict__ Vo) {
  int mat = blockIdx.z;  // 0=q 1=k 2=v
  const unsigned short* W = (mat == 0) ? Wq : ((mat == 1) ? Wk : Wv);
  unsigned short* Out = (mat == 0) ? Qo : ((mat == 1) ? Ko : Vo);
  int m0 = blockIdx.x * 128, n0 = blockIdx.y * 128;

  GEMM128_BODY(X, W, m0, n0)

#pragma unroll
  for (int n = 0; n < 4; ++n) {
    int col = n0 + wn * 64 + n * 16 + l15;  // 0..1023
    int h = col >> 6;
    int d = col & 63;
    int pi = d >> 1;
    bool odd = (d & 1) != 0;
    size_t hb = (size_t)h * 2048 * 64;
#pragma unroll
    for (int m = 0; m < 4; ++m) {
      int row0 = m0 + wm * 64 + m * 16 + quad * 4;  // rows row0..row0+3
      int b = row0 >> 11;
      int s0 = row0 & 2047;
      size_t base = (size_t)b * 16 * 2048 * 64 + hb;
      if (mat == 2) {
        // V: packed b64 store along s (transposed layout [d][s])
        ushort4 pv;
        pv.x = f2bf(acc[m][n][0]);
        pv.y = f2bf(acc[m][n][1]);
        pv.z = f2bf(acc[m][n][2]);
        pv.w = f2bf(acc[m][n][3]);
        *(ushort4*)(Out + base + (size_t)d * 2048 + s0) = pv;
      } else {
#pragma unroll
        for (int i = 0; i < 4; ++i) {
          int s = s0 + i;
          float v = acc[m][n][i];
          float p = __shfl_xor(v, 1);
          float c = ctab[s * 32 + pi];
          float sn = stab[s * 32 + pi];
          float res = odd ? fmaf(p, sn, v * c) : fmaf(v, c, -p * sn);
          if (mat == 0) res *= 0.125f;  // fold 1/sqrt(dk) into Q
          Out[base + (size_t)s * 64 + d] = f2bf(res);
        }
      }
    }
  }
}

// ---------------------------------------------------------------------------
// Output projection: out = Oc @ Wo^T, tiled MFMA GEMM, fp32 store
// ---------------------------------------------------------------------------
__global__ __launch_bounds__(256) void oproj_mfma(
    const unsigned short* __restrict__ A, const unsigned short* __restrict__ Wo,
    float* __restrict__ Out) {
  int m0 = blockIdx.x * 128, n0 = blockIdx.y * 128;

  GEMM128_BODY(A, Wo, m0, n0)

#pragma unroll
  for (int m = 0; m < 4; ++m) {
#pragma unroll
    for (int n = 0; n < 4; ++n) {
      int col = n0 + wn * 64 + n * 16 + l15;
#pragma unroll
      for (int i = 0; i < 4; ++i) {
        int row = m0 + wm * 64 + m * 16 + quad * 4 + i;
        Out[(size_t)row * 1024 + col] = acc[m][n][i];
      }
    }
  }
}

// ---------------------------------------------------------------------------
// Flash attention, transposed-score form + load-balanced (qtile,bh) swizzle.
//  S^T = K·Q^T  -> per-lane q (= lane&15): softmax is in-lane + 2 shfl_xor.
//  O^T = V^T·P^T -> per-lane q: alpha-rescale and 1/l are pure per-lane.
// Register-prefetch double buffering for K/V staging (hides global latency).
// ---------------------------------------------------------------------------
#define LKS 72

__global__ __launch_bounds__(256) void attn_flash(
    const unsigned short* __restrict__ Q, const unsigned short* __restrict__ K,
    const unsigned short* __restrict__ Vt, unsigned short* __restrict__ Oc) {
  __shared__ unsigned short lK[64 * LKS];      // [kj][d]
  __shared__ unsigned short lV[64 * LKS];      // [d][kj]
  __shared__ unsigned short lP[4][16 * LKS];   // per-wave [q][kj]

  int tid = threadIdx.x;
  int wave = tid >> 6, lane = tid & 63;
  int l15 = lane & 15, quad = lane >> 4;

  // load-balance swizzle: co-resident blocks {id, id+256, id+512, id+768}
  // get qtiles {x, 31-x, (15-x)&31, (16+x)&31} -> 66 iters per CU for all x.
  int xb_ = blockIdx.x;          // 0..31
  int yb_ = blockIdx.y;          // 0..31
  int jb = yb_ >> 3, ib = yb_ & 7;
  int qtile;
  if (jb == 0)      qtile = xb_;
  else if (jb == 1) qtile = 31 - xb_;
  else if (jb == 2) qtile = (15 - xb_) & 31;
  else              qtile = (16 + xb_) & 31;
  int bh = ib * 4 + jb;

  size_t base = (size_t)bh * 2048 * 64;
  int qbase = qtile * 64;

  // Q rows as B-operand fragments (B[k=d][n=q]); q = wavebase + l15
  const unsigned short* qrow = Q + base + (size_t)(qbase + wave * 16 + l15) * 64;
  short8 qb0 = *(const short8*)(qrow + quad * 8);
  short8 qb1 = *(const short8*)(qrow + 32 + quad * 8);

  floatx4 o[4];          // O^T[d = n*16+quad*4+reg][q = l15]
  float m_i = -1e30f, l_i = 0.f;   // per-lane softmax state (q = l15)
#pragma unroll
  for (int n = 0; n < 4; ++n) o[n] = (floatx4){0.f, 0.f, 0.f, 0.f};

  // staging slots: thread covers rows r0,r1, chunk e0
  int r0 = tid >> 3, e0 = (tid & 7) * 8;
  int r1 = r0 + 32;

  // prefetch kt=0
  const unsigned short* kp = K + base;
  const unsigned short* vp = Vt + base;
  short8 pk0 = *(const short8*)(kp + r0 * 64 + e0);
  short8 pk1 = *(const short8*)(kp + r1 * 64 + e0);
  short8 pv0 = *(const short8*)(vp + (size_t)r0 * 2048 + e0);
  short8 pv1 = *(const short8*)(vp + (size_t)r1 * 2048 + e0);

  for (int kt = 0; kt <= qtile; ++kt) {
    __syncthreads();   // all waves done reading lK/lV from previous iter
    *(short8*)(lK + r0 * LKS + e0) = pk0;
    *(short8*)(lK + r1 * LKS + e0) = pk1;
    *(short8*)(lV + r0 * LKS + e0) = pv0;
    *(short8*)(lV + r1 * LKS + e0) = pv1;
    __syncthreads();

    if (kt < qtile) {  // prefetch next tile; consumed at next iter's LDS write
      const unsigned short* kn = K + base + (size_t)(kt + 1) * 64 * 64;
      const unsigned short* vn = Vt + base + (kt + 1) * 64;
      pk0 = *(const short8*)(kn + r0 * 64 + e0);
      pk1 = *(const short8*)(kn + r1 * 64 + e0);
      pv0 = *(const short8*)(vn + (size_t)r0 * 2048 + e0);
      pv1 = *(const short8*)(vn + (size_t)r1 * 2048 + e0);
    }

    // ---- S^T = K·Q^T : sc[sub][i] is score for kpos = sub*16+quad*4+i, q=l15
    float sc[4][4];
#pragma unroll
    for (int sub = 0; sub < 4; ++sub) {
      const unsigned short* kr = lK + (sub * 16 + l15) * LKS + quad * 8;
      short8 a0 = *(const short8*)(kr);
      short8 a1 = *(const short8*)(kr + 32);
      floatx4 s = {0.f, 0.f, 0.f, 0.f};
      s = __builtin_amdgcn_mfma_f32_16x16x32_bf16(a0, qb0, s, 0, 0, 0);
      s = __builtin_amdgcn_mfma_f32_16x16x32_bf16(a1, qb1, s, 0, 0, 0);
#pragma unroll
      for (int i = 0; i < 4; ++i) sc[sub][i] = s[i];
    }

    // ---- causal mask (diagonal tile only): k-within > q-within
    if (kt == qtile) {
      int qin = wave * 16 + l15;
#pragma unroll
      for (int sub = 0; sub < 4; ++sub)
#pragma unroll
        for (int i = 0; i < 4; ++i)
          if (sub * 16 + quad * 4 + i > qin) sc[sub][i] = -1e30f;
    }

    // ---- online softmax: in-lane tree + 2 cross-quad shuffles
    float mb = sc[0][0];
#pragma unroll
    for (int sub = 0; sub < 4; ++sub)
#pragma unroll
      for (int i = 0; i < 4; ++i) mb = fmaxf(mb, sc[sub][i]);
    mb = fmaxf(mb, __shfl_xor(mb, 16));
    mb = fmaxf(mb, __shfl_xor(mb, 32));

    float mn = fmaxf(m_i, mb);
    float al = __expf(m_i - mn);
    m_i = mn;
    float rs = 0.f;
#pragma unroll
    for (int sub = 0; sub < 4; ++sub)
#pragma unroll
      for (int i = 0; i < 4; ++i) {
        float p = __expf(sc[sub][i] - mn);
        sc[sub][i] = p;
        rs += p;
      }
    rs += __shfl_xor(rs, 16);
    rs += __shfl_xor(rs, 32);
    l_i = l_i * al + rs;

    // per-lane rescale of O^T columns (q = l15 matches softmax state)
#pragma unroll
    for (int n = 0; n < 4; ++n) {
      o[n][0] *= al; o[n][1] *= al; o[n][2] *= al; o[n][3] *= al;
    }

    // ---- P^T -> lP as [q][k] rows, packed 4-wide
    unsigned short* pw = lP[wave];
#pragma unroll
    for (int sub = 0; sub < 4; ++sub) {
      ushort4 pq;
      pq.x = f2bf(sc[sub][0]); pq.y = f2bf(sc[sub][1]);
      pq.z = f2bf(sc[sub][2]); pq.w = f2bf(sc[sub][3]);
      *(ushort4*)(pw + l15 * LKS + sub * 16 + quad * 4) = pq;
    }

    const unsigned short* pr = pw + l15 * LKS + quad * 8;
    short8 pa0 = *(const short8*)(pr);
    short8 pa1 = *(const short8*)(pr + 32);

    // ---- O^T += V^T·P^T : A = lV rows (d), B = lP rows (q)
#pragma unroll
    for (int n = 0; n < 4; ++n) {
      const unsigned short* vr = lV + (n * 16 + l15) * LKS + quad * 8;
      short8 vb0 = *(const short8*)(vr);
      short8 vb1 = *(const short8*)(vr + 32);
      o[n] = __builtin_amdgcn_mfma_f32_16x16x32_bf16(vb0, pa0, o[n], 0, 0, 0);
      o[n] = __builtin_amdgcn_mfma_f32_16x16x32_bf16(vb1, pa1, o[n], 0, 0, 0);
    }
  }

  // ---- epilogue: per-lane 1/l, packed stores; lane owns row s = qbase+wave*16+l15
  int b = bh >> 4, h = bh & 15;
  float inv = 1.f / l_i;
  int s = qbase + wave * 16 + l15;
  size_t orow = (size_t)(b * 2048 + s) * 1024 + h * 64;
#pragma unroll
  for (int n = 0; n < 4; ++n) {
    ushort4 ov;
    ov.x = f2bf(o[n][0] * inv);
    ov.y = f2bf(o[n][1] * inv);
    ov.z = f2bf(o[n][2] * inv);
    ov.w = f2bf(o[n][3] * inv);
    *(ushort4*)(Oc + orow + n * 16 + quad * 4) = ov;
  }
}

// ---------------------------------------------------------------------------
extern "C" void kernel_launch(void* const* d_in, const int* in_sizes, int n_in,
                              void* d_out, int out_size, void* d_ws, size_t ws_size,
                              hipStream_t stream) {
  const float* x  = (const float*)d_in[0];
  const int* tokpos = (const int*)d_in[1];
  const float* Wq = (const float*)d_in[2];
  const float* Wk = (const float*)d_in[3];
  const float* Wv = (const float*)d_in[4];
  const float* Wo = (const float*)d_in[5];
  float* out = (float*)d_out;

  float* ws = (float*)d_ws;
  float* ctab = ws;
  float* stab = ctab + 65536;
  unsigned short* u = (unsigned short*)(stab + 65536);
  unsigned short* Qb  = u;
  unsigned short* Kb  = Qb + 4194304;
  unsigned short* Vb  = Kb + 4194304;   // transposed [bh][d][s]
  unsigned short* Oc  = Vb + 4194304;
  unsigned short* xb  = Oc + 4194304;
  unsigned short* Wqb = xb + 4194304;
  unsigned short* Wkb = Wqb + 1048576;
  unsigned short* Wvb = Wkb + 1048576;
  unsigned short* Wob = Wvb + 1048576;

  cvt_all<<<dim3(4096, 5), 256, 0, stream>>>(
      (const float4*)x, (const float4*)Wq, (const float4*)Wk,
      (const float4*)Wv, (const float4*)Wo,
      (ushort4*)xb, (ushort4*)Wqb, (ushort4*)Wkb, (ushort4*)Wvb, (ushort4*)Wob);

  rope_tables<<<256, 256, 0, stream>>>(tokpos, ctab, stab);
  qkv_mfma<<<dim3(32, 8, 3), 256, 0, stream>>>(
      xb, Wqb, Wkb, Wvb, ctab, stab, Qb, Kb, Vb);
  attn_flash<<<dim3(32, 32), 256, 0, stream>>>(Qb, Kb, Vb, Oc);
  oproj_mfma<<<dim3(32, 8), 256, 0, stream>>>(Oc, Wob, out);
}